// Round 5
// baseline (236.040 us; speedup 1.0000x reference)
//
#include <hip/hip_runtime.h>
#include <hip/hip_bf16.h>

typedef __attribute__((ext_vector_type(8))) short short8;
typedef __attribute__((ext_vector_type(4))) short short4v;
typedef __attribute__((ext_vector_type(4))) float f32x4;

__device__ __forceinline__ short f2bf(float f) {
    union { float f; unsigned u; } v; v.f = f;
    unsigned r = (v.u + 0x7fffu + ((v.u >> 16) & 1u)) >> 16;
    return (short)r;
}
__device__ __forceinline__ float bf2f(short s) {
    union { unsigned u; float f; } v; v.u = ((unsigned)(unsigned short)s) << 16;
    return v.f;
}
__device__ __forceinline__ f32x4 zero4() { f32x4 z = {0.f, 0.f, 0.f, 0.f}; return z; }

__device__ __forceinline__ void gl16(const void* g, void* l) {
    __builtin_amdgcn_global_load_lds(
        (const __attribute__((address_space(1))) void*)g,
        (__attribute__((address_space(3))) void*)l, 16, 0, 0);
}

// ---------------------------------------------------------------------------
// convertA: fp32 -> bf16 (before proj). z=0: qb  z=1: kb  z=2: Wqb  z=3: Wkb
// ---------------------------------------------------------------------------
__global__ __launch_bounds__(256) void convertA_kernel(
    const float* __restrict__ q, const float* __restrict__ k,
    const float* __restrict__ Wq, const float* __restrict__ Wk,
    short* __restrict__ qb, short* __restrict__ kb,
    short* __restrict__ Wqb, short* __restrict__ Wkb)
{
    const int e0 = (blockIdx.x * 256 + threadIdx.x) * 8;
    const float* src; short* dst; int n;
    switch (blockIdx.z) {
    case 0:  n = 6291456; src = q + e0;  dst = qb;  break;
    case 1:  n = 6291456; src = k + e0;  dst = kb;  break;
    case 2:  n = 786432;  src = Wq + e0; dst = Wqb; break;
    default: n = 786432;  src = Wk + e0; dst = Wkb; break;
    }
    if (e0 >= n) return;
    float4 f0 = ((const float4*)src)[0];
    float4 f1 = ((const float4*)src)[1];
    short8 o;
    o[0]=f2bf(f0.x); o[1]=f2bf(f0.y); o[2]=f2bf(f0.z); o[3]=f2bf(f0.w);
    o[4]=f2bf(f1.x); o[5]=f2bf(f1.y); o[6]=f2bf(f1.z); o[7]=f2bf(f1.w);
    *(short8*)(dst + e0) = o;
}

// ---------------------------------------------------------------------------
// bf16 GEMM, BM=64 BN=128 BK=64, gl16 staging (round-3: M-split of the proven
// gemm97 core for grid balance: 768 blocks ~ 3/CU instead of 384 ~ 1.5/CU).
// Waves 2x2 (32x64 each), acc[2][4]. ROPE epilogue logic unchanged.
// ---------------------------------------------------------------------------
template<bool ROPE>
__device__ __forceinline__ void gemm97_bm64(
    const short* __restrict__ A, const short* __restrict__ B, short* __restrict__ Cp,
    int K, int lda, int ldb, int ldc, short* As, short* Bs)
{
    const int bm = blockIdx.y * 64;
    const int bn = blockIdx.x * 128;
    const int tid = threadIdx.x;
    const int w = tid >> 6;
    const int lane = tid & 63;
    const int l15 = lane & 15;
    const int quad = lane >> 4;
    const int wm = (w >> 1) * 32;
    const int wn = (w & 1) * 64;

    // staging addresses: A wave covers 16 rows (1 gl16/plane), B 32 rows (2/plane)
    const int srA = w * 16 + (lane >> 2);
    const int srB = w * 32 + (lane >> 2);
    const int sc  = (lane & 3) * 8;
    const short* ga = A + (size_t)(bm + srA) * lda + sc;
    const short* gb = B + (size_t)(bn + srB) * ldb + sc;

    f32x4 acc[2][4];
#pragma unroll
    for (int i = 0; i < 2; i++)
#pragma unroll
        for (int j = 0; j < 4; j++) acc[i][j] = zero4();

    for (int k0 = 0; k0 < K; k0 += 64) {
        __syncthreads();
#pragma unroll
        for (int p = 0; p < 2; p++) {
            gl16(ga + k0 + p * 32,                    &As[p * 2048 + (w * 16) * 32]);
            gl16(gb + k0 + p * 32,                    &Bs[p * 4096 + (w * 32) * 32]);
            gl16(gb + k0 + p * 32 + (size_t)16 * ldb, &Bs[p * 4096 + (w * 32 + 16) * 32]);
        }
        __syncthreads();

        short8 af[2][2], bf[2][4];
#pragma unroll
        for (int p = 0; p < 2; p++) {
#pragma unroll
            for (int i = 0; i < 2; i++)
                af[p][i] = *(const short8*)&As[p * 2048 + (wm + i * 16 + l15) * 32 + quad * 8];
#pragma unroll
            for (int j = 0; j < 4; j++)
                bf[p][j] = *(const short8*)&Bs[p * 4096 + (wn + j * 16 + l15) * 32 + quad * 8];
        }
#pragma unroll
        for (int i = 0; i < 2; i++)
#pragma unroll
            for (int j = 0; j < 4; j++) {
                acc[i][j] = __builtin_amdgcn_mfma_f32_16x16x32_bf16(af[0][i], bf[0][j], acc[i][j], 0, 0, 0);
                acc[i][j] = __builtin_amdgcn_mfma_f32_16x16x32_bf16(af[1][i], bf[1][j], acc[i][j], 0, 0, 0);
            }
    }

#pragma unroll
    for (int i = 0; i < 2; i++)
#pragma unroll
        for (int j = 0; j < 4; j++) {
            const int col = bn + wn + j * 16 + l15;
            const int row0 = bm + wm + i * 16 + quad * 4;
            if constexpr (ROPE) {
                const int pairi = (col & 127) >> 1;   // same for both lanes of a pair
                const float freq = exp2f(-(float)(2 * pairi) * (13.287712379549449f / 128.0f));
                const bool even = (l15 & 1) == 0;
#pragma unroll
                for (int r = 0; r < 4; r++) {
                    const float own = acc[i][j][r];
                    const float other = __shfl_xor(own, 1, 64);
                    const float pos = (float)((row0 + r) & 2047);
                    const float ang = pos * freq;
                    const float n = rintf(ang * 0.15915494309189535f);
                    const float rr = (ang - n * 6.28125f) - n * 1.9353071795864769e-3f;
                    float s, c;
                    __sincosf(rr, &s, &c);
                    const float x1 = even ? own : other;
                    const float x2 = even ? other : own;
                    const float res = even ? (x1 * c - x2 * s) : (x1 * s + x2 * c);
                    Cp[(size_t)(row0 + r) * ldc + col] = f2bf(res);
                }
            } else {
#pragma unroll
                for (int r = 0; r < 4; r++)
                    Cp[(size_t)(row0 + r) * ldc + col] = f2bf(acc[i][j][r]);
            }
        }
}

// ---------------------------------------------------------------------------
// fp32-input GEMM, BM=64 BN=128 BK=32 (M-split of the proven f32_bt_T core):
// C^T bf16 out (transposed store).
// ---------------------------------------------------------------------------
__device__ __forceinline__ void gemm_f32T_bm64(
    const float* __restrict__ A, const float* __restrict__ Bw, short* __restrict__ Cp,
    int K, int lda, int ldb, int ldc, short* As, short* Bs)
{
    const int bm = blockIdx.y * 64;
    const int bn = blockIdx.x * 128;
    const int tid = threadIdx.x;
    const int w = tid >> 6;
    const int lane = tid & 63;
    const int l15 = lane & 15;
    const int quad = lane >> 4;
    const int wm = (w >> 1) * 32;
    const int wn = (w & 1) * 64;
    // A staging: 64 rows x 32 cols, thread = (row tid>>2, col (tid&3)*8)
    const int srA = tid >> 2;
    const int scA = (tid & 3) * 8;
    // B staging: 128 rows x 32 cols, thread = (row tid>>1, col (tid&1)*16)
    const int srB = tid >> 1;
    const int scB = (tid & 1) * 16;

    f32x4 acc[2][4];
#pragma unroll
    for (int i = 0; i < 2; i++)
#pragma unroll
        for (int j = 0; j < 4; j++) acc[i][j] = zero4();

    for (int k0 = 0; k0 < K; k0 += 32) {
        __syncthreads();
        {
            const float* src = A + (size_t)(bm + srA) * lda + k0 + scA;
            short* dst = &As[srA * 40 + scA];
            const float4* s4 = (const float4*)src;
            float4 f0 = s4[0], f1 = s4[1];
            short8 t0;
            t0[0]=f2bf(f0.x); t0[1]=f2bf(f0.y); t0[2]=f2bf(f0.z); t0[3]=f2bf(f0.w);
            t0[4]=f2bf(f1.x); t0[5]=f2bf(f1.y); t0[6]=f2bf(f1.z); t0[7]=f2bf(f1.w);
            *(short8*)dst = t0;
        }
        {
            const float* src = Bw + (size_t)(bn + srB) * ldb + k0 + scB;
            short* dst = &Bs[srB * 40 + scB];
            const float4* s4 = (const float4*)src;
            float4 f0 = s4[0], f1 = s4[1], f2 = s4[2], f3 = s4[3];
            short8 t0, t1;
            t0[0]=f2bf(f0.x); t0[1]=f2bf(f0.y); t0[2]=f2bf(f0.z); t0[3]=f2bf(f0.w);
            t0[4]=f2bf(f1.x); t0[5]=f2bf(f1.y); t0[6]=f2bf(f1.z); t0[7]=f2bf(f1.w);
            t1[0]=f2bf(f2.x); t1[1]=f2bf(f2.y); t1[2]=f2bf(f2.z); t1[3]=f2bf(f2.w);
            t1[4]=f2bf(f3.x); t1[5]=f2bf(f3.y); t1[6]=f2bf(f3.z); t1[7]=f2bf(f3.w);
            *(short8*)dst = t0; *(short8*)(dst + 8) = t1;
        }
        __syncthreads();

        short8 af[2], bfr[4];
#pragma unroll
        for (int i = 0; i < 2; i++)
            af[i] = *(const short8*)&As[(wm + i * 16 + l15) * 40 + quad * 8];
#pragma unroll
        for (int j = 0; j < 4; j++)
            bfr[j] = *(const short8*)&Bs[(wn + j * 16 + l15) * 40 + quad * 8];
#pragma unroll
        for (int i = 0; i < 2; i++)
#pragma unroll
            for (int j = 0; j < 4; j++)
                acc[i][j] = __builtin_amdgcn_mfma_f32_16x16x32_bf16(af[i], bfr[j], acc[i][j], 0, 0, 0);
    }

#pragma unroll
    for (int i = 0; i < 2; i++)
#pragma unroll
        for (int j = 0; j < 4; j++) {
            const int col = bn + wn + j * 16 + l15;
            const int row0 = bm + wm + i * 16 + quad * 4;
            short4v p;
#pragma unroll
            for (int r = 0; r < 4; r++) p[r] = f2bf(acc[i][j][r]);
            *(short4v*)&Cp[(size_t)col * ldc + row0] = p;
        }
}

// ---------------------------------------------------------------------------
// Mixed GEMM (round-1 proven): A bf16, B fp32 (converted in staging), fp32 out.
// ---------------------------------------------------------------------------
__device__ __forceinline__ void gemm_mixed_f32out(
    const short* __restrict__ A, const float* __restrict__ Bw, float* __restrict__ Cp,
    int K, int lda, int ldb, int ldc, short* As, short* Bs)
{
    const int bm = blockIdx.y * 128;
    const int bn = blockIdx.x * 128;
    const int tid = threadIdx.x;
    const int w = tid >> 6;
    const int lane = tid & 63;
    const int l15 = lane & 15;
    const int quad = lane >> 4;
    const int wm = (w >> 1) * 64;
    const int wn = (w & 1) * 64;
    const int srow = tid >> 1;
    const int scol = (tid & 1) * 16;

    f32x4 acc[4][4];
#pragma unroll
    for (int i = 0; i < 4; i++)
#pragma unroll
        for (int j = 0; j < 4; j++) acc[i][j] = zero4();

    for (int k0 = 0; k0 < K; k0 += 32) {
        __syncthreads();
        {
            const short* src = A + (size_t)(bm + srow) * lda + k0 + scol;
            short* dst = &As[srow * 40 + scol];
            const uint4* s4 = (const uint4*)src;
            uint4 a = s4[0], b = s4[1];
            *(uint4*)dst = a; *(uint4*)(dst + 8) = b;
        }
        {
            const float* src = Bw + (size_t)(bn + srow) * ldb + k0 + scol;
            short* dst = &Bs[srow * 40 + scol];
            const float4* s4 = (const float4*)src;
            float4 f0 = s4[0], f1 = s4[1], f2 = s4[2], f3 = s4[3];
            short8 t0, t1;
            t0[0]=f2bf(f0.x); t0[1]=f2bf(f0.y); t0[2]=f2bf(f0.z); t0[3]=f2bf(f0.w);
            t0[4]=f2bf(f1.x); t0[5]=f2bf(f1.y); t0[6]=f2bf(f1.z); t0[7]=f2bf(f1.w);
            t1[0]=f2bf(f2.x); t1[1]=f2bf(f2.y); t1[2]=f2bf(f2.z); t1[3]=f2bf(f2.w);
            t1[4]=f2bf(f3.x); t1[5]=f2bf(f3.y); t1[6]=f2bf(f3.z); t1[7]=f2bf(f3.w);
            *(short8*)dst = t0; *(short8*)(dst + 8) = t1;
        }
        __syncthreads();

        short8 af[4], bfr[4];
#pragma unroll
        for (int i = 0; i < 4; i++)
            af[i] = *(const short8*)&As[(wm + i * 16 + l15) * 40 + quad * 8];
#pragma unroll
        for (int j = 0; j < 4; j++)
            bfr[j] = *(const short8*)&Bs[(wn + j * 16 + l15) * 40 + quad * 8];
#pragma unroll
        for (int i = 0; i < 4; i++)
#pragma unroll
            for (int j = 0; j < 4; j++)
                acc[i][j] = __builtin_amdgcn_mfma_f32_16x16x32_bf16(af[i], bfr[j], acc[i][j], 0, 0, 0);
    }

#pragma unroll
    for (int i = 0; i < 4; i++)
#pragma unroll
        for (int j = 0; j < 4; j++) {
            const int col = bn + wn + j * 16 + l15;
            const int row0 = bm + wm + i * 16 + quad * 4;
#pragma unroll
            for (int r = 0; r < 4; r++)
                Cp[(size_t)(row0 + r) * ldc + col] = acc[i][j][r];
        }
}

// z=0: qh = rope(qb@Wqb^T); z=1: kh = rope(kb@Wkb^T); z=2: vT = (v_mid@Wv^T)^T
// BM=64 tiles: grid (4, 64, 3) = 768 blocks ~ 3/CU for balance + latency hiding.
__global__ __launch_bounds__(256) void proj_kernel(
    const short* __restrict__ qb, const short* __restrict__ kb, const float* __restrict__ v,
    const short* __restrict__ Wqb, const short* __restrict__ Wkb, const float* __restrict__ Wv,
    short* __restrict__ qh, short* __restrict__ kh, short* __restrict__ vT)
{
    __shared__ short smem[12288];   // 24 KB: z0/z1: As 4096 + Bs 8192; z2: 2560+5120
    switch (blockIdx.z) {
    case 0:  gemm97_bm64<true>(qb, Wqb, qh, 1536, 1536, 1536, 512, smem, smem + 4096); break;
    case 1:  gemm97_bm64<true>(kb, Wkb, kh, 1536, 1536, 1536, 512, smem, smem + 4096); break;
    default: gemm_f32T_bm64(v + 512, Wv, vT, 512, 1536, 512, 4096, smem, smem + 2560); break;
    }
}

// out[4096,1536] = attn[4096,512] @ Wo[:, :512]^T — convertB fused (B fp32 staging)
__global__ __launch_bounds__(256) void outproj_kernel(
    const short* __restrict__ attn, const float* __restrict__ Wo, float* __restrict__ out)
{
    __shared__ short smem[2][5120];
    gemm_mixed_f32out(attn, Wo, out, 512, 512, 1536, 1536, smem[0], smem[1]);
}

// ---------------------------------------------------------------------------
// Flash attention v11: balanced chunk-pairing on the v10 structure.
// Block = (b, h, pair p): processes q-chunks [32p,32p+32) then [(63-p)*32,...)
// SEQUENTIALLY -> constant 65 KV-tiles per block, exactly 9 supersteps for
// every p (was: 16 supersteps on the worst block, mean 8.4 -> ~2x makespan).
// 16 waves = 2 row-groups (16 q-rows) x 8 KV-parity. Superstep = 8 KV tiles:
// wave (0,tl) stages K of tile tl (8 gl16), wave (1,tl) stages V of tile tl.
// Swizzle on GLOBAL source (rule #21), same XOR scheme as v10.
// Merge per chunk: 2 rounds of 8-way O/L reduction through dead K-buffer.
// Grid 256 = 8 (b,h) x 32 pairs; id&7 XCD-pins all blocks of one (b,h) to one
// XCD (K/V ~1MB stays L2-resident). LDS 148 KB, 1 block/CU (unchanged regime).
// ---------------------------------------------------------------------------
__global__ __launch_bounds__(1024, 4) void flash_kernel(
    const short* __restrict__ qh, const short* __restrict__ kh,
    const short* __restrict__ vT, short* __restrict__ attn)
{
    // Ks: 8 tiles [32][128] bf16 swizzled (64 KB) | Vs: 8 tiles [128][32]
    // bf16 swizzled (64 KB) | Ps: 16 x 640 shorts (20 KB). Total 148 KB.
    // Merge aliases: Om = (float*)smem (8x16x128 = 64 KB over Ks),
    //                Lw = (float*)(smem+32768) (512 B over Vs).
    __shared__ __align__(16) short smem[75776];
    short* Ks = smem;               // 32768 shorts
    short* Vs = smem + 32768;       // 32768 shorts
    short* Ps = smem + 65536;       // 10240 shorts

    const int id = blockIdx.x;      // 0..255
    const int hb = id & 7;
    const int b = hb & 1;
    const int h = hb >> 1;
    const int p = id >> 3;          // pair index 0..31
    const int tid = threadIdx.x;
    const int W = tid >> 6;         // wave 0..15
    const int lane = tid & 63;
    const int l15 = lane & 15;
    const int quad = lane >> 4;
    const int g = W >> 3;           // row-group 0..1
    const int tl = W & 7;           // KV parity 0..7

    const float scale = 0.08838834764831845f;
    const float MFIX = 24.0f;

    const short* kbp = kh + (size_t)(b * 2048) * 512 + h * 128;
    const short* vbp = vT + (size_t)(h * 128) * 4096 + b * 2048;

    // K staging (wave g==0): gl16 j covers local rows 4j..4j+3; r = 4j+quad,
    // col swizzle l15 ^ (r&7) where r&7 = 4*(j&1)+quad -> two base pointers.
    const short* gkE = kbp + (size_t)quad * 512 + (l15 ^ quad) * 8;
    const short* gkO = kbp + (size_t)quad * 512 + (l15 ^ (quad + 4)) * 8;
    // V staging (wave g==1): gl16 j covers local d-rows 16j..16j+15; r&3
    // depends only on (lane>>2)&3 -> single base pointer.
    const int vq = lane >> 2;
    const short* gv = vbp + (size_t)vq * 4096 + ((lane & 3) ^ (vq & 3)) * 8;

    const int kmask = (l15 & 7) << 4;
    const int vmask = (l15 & 3) << 4;
    short* pw = &Ps[W * 640];
    short* ksw = &Ks[tl * 4096];
    short* vsw = &Vs[tl * 4096];

#pragma unroll 1
    for (int c = 0; c < 2; ++c) {
        const int q0c = (c ? (63 - p) : p) * 32;
        const int nt = (q0c + 63) >> 5;      // KV tiles for this chunk
        const int nss = (nt + 7) >> 3;       // supersteps (sum over c == 9)
        const int qr0 = q0c + g * 16;

        const short* qrow = qh + (size_t)(b * 2048 + qr0 + l15) * 512 + h * 128;
        short8 aq[4];
#pragma unroll
        for (int kk = 0; kk < 4; kk++)
            aq[kk] = *(const short8*)&qrow[kk * 32 + quad * 8];

        f32x4 o[8];
#pragma unroll
        for (int dt = 0; dt < 8; dt++) o[dt] = zero4();
        float lsum[4] = {0.f, 0.f, 0.f, 0.f};

        for (int s = 0; s < nss; ++s) {
            const int t = s * 8 + tl;        // wave-uniform tile index
            if (t < nt) {
                const size_t ko = (size_t)t * 32;
                if (g == 0) {
#pragma unroll
                    for (int j = 0; j < 8; ++j) {
                        const short* src = (j & 1 ? gkO : gkE) + (ko + 4 * j) * 512;
                        gl16(src, &ksw[j * 512 + lane * 8]);
                    }
                } else {
#pragma unroll
                    for (int j = 0; j < 8; ++j)
                        gl16(gv + (size_t)(16 * j) * 4096 + ko, &vsw[j * 512 + lane * 8]);
                }
            }
            __syncthreads();   // all 8 tiles staged & visible

            if (t < nt) {
                const int kb0 = t * 32;
                // ---- S = Q K^T (16q x 32k) from swizzled LDS ----
                f32x4 sc[2];
#pragma unroll
                for (int ct = 0; ct < 2; ct++) {
                    sc[ct] = zero4();
                    const char* kr = (const char*)&ksw[(ct * 16 + l15) * 128];
#pragma unroll
                    for (int kk = 0; kk < 4; kk++) {
                        short8 bk = *(const short8*)(kr + ((kk * 64 + quad * 16) ^ kmask));
                        sc[ct] = __builtin_amdgcn_mfma_f32_16x16x32_bf16(aq[kk], bk, sc[ct], 0, 0, 0);
                    }
                }

                // ---- V frags from swizzled LDS ----
                short8 bv[8];
#pragma unroll
                for (int dt = 0; dt < 8; dt++) {
                    const char* vr = (const char*)&vsw[(dt * 16 + l15) * 32];
                    bv[dt] = *(const short8*)(vr + ((quad * 16) ^ vmask));
                }

                // ---- fixed-max softmax: p = exp(s*scale - M), masked -> 0 ----
                const int rbase = qr0 + quad * 4;
                float pm[2][4];
#pragma unroll
                for (int ct = 0; ct < 2; ct++) {
                    const int kcol = kb0 + ct * 16 + l15;
#pragma unroll
                    for (int r = 0; r < 4; r++) {
                        const float e = __expf(sc[ct][r] * scale - MFIX);
                        const float pv = (kcol > rbase + r) ? 0.0f : e;
                        pm[ct][r] = pv;
                        lsum[r] += pv;
                    }
                }

                // ---- P -> per-wave LDS (A-operand layout); intra-wave ----
#pragma unroll
                for (int ct = 0; ct < 2; ct++)
#pragma unroll
                    for (int r = 0; r < 4; r++)
                        pw[(quad * 4 + r) * 40 + ct * 16 + l15] = f2bf(pm[ct][r]);
                short8 ap = *(const short8*)&pw[l15 * 40 + quad * 8];

                // ---- O += P V ----
#pragma unroll
                for (int dt = 0; dt < 8; dt++)
                    o[dt] = __builtin_amdgcn_mfma_f32_16x16x32_bf16(ap, bv[dt], o[dt], 0, 0, 0);
            }
            __syncthreads();   // before next superstep overwrites LDS
        }

        // ---- merge this chunk: 2 rounds (one per row-group), 8 partials ----
#pragma unroll
        for (int r = 0; r < 4; r++) {
#pragma unroll
            for (int off = 1; off < 16; off <<= 1)
                lsum[r] += __shfl_xor(lsum[r], off, 64);
        }

        float* Om = (float*)smem;             // [8][16][128] f32 (over Ks)
        float* Lw = (float*)(smem + 32768);   // [8][16] f32 (over Vs)

        for (int rr = 0; rr < 2; ++rr) {
            if (g == rr) {
#pragma unroll
                for (int r = 0; r < 4; r++) {
                    const int row = quad * 4 + r;
#pragma unroll
                    for (int dt = 0; dt < 8; dt++)
                        Om[(tl * 16 + row) * 128 + dt * 16 + l15] = o[dt][r];
                    if (l15 == 0) Lw[tl * 16 + row] = lsum[r];
                }
            }
            __syncthreads();
            {
                const int row = tid >> 6;         // 0..15
                const int d0 = (tid & 63) * 2;    // 0..126
                float L = 0.f;
#pragma unroll
                for (int i = 0; i < 8; i++) L += Lw[i * 16 + row];
                const float rL = 1.0f / L;
                float s0 = 0.f, s1 = 0.f;
#pragma unroll
                for (int i = 0; i < 8; i++) {
                    s0 += Om[(i * 16 + row) * 128 + d0];
                    s1 += Om[(i * 16 + row) * 128 + d0 + 1];
                }
                const unsigned pack = ((unsigned)(unsigned short)f2bf(s0 * rL))
                                    | (((unsigned)(unsigned short)f2bf(s1 * rL)) << 16);
                *(unsigned*)&attn[(size_t)(b * 2048 + q0c + rr * 16 + row) * 512 + h * 128 + d0] = pack;
            }
            __syncthreads();
        }
    }
}

extern "C" void kernel_launch(void* const* d_in, const int* in_sizes, int n_in,
                              void* d_out, int out_size, void* d_ws, size_t ws_size,
                              hipStream_t stream) {
    const float* q  = (const float*)d_in[0];
    const float* k  = (const float*)d_in[1];
    const float* v  = (const float*)d_in[2];
    const float* Wq = (const float*)d_in[3];
    const float* Wk = (const float*)d_in[4];
    const float* Wv = (const float*)d_in[5];
    const float* Wo = (const float*)d_in[6];
    float* out = (float*)d_out;

    const size_t MB = 1024 * 1024;
    // ws (16 MB, proven):
    char* ws = (char*)d_ws;
    short* qh   = (short*)(ws);               // [4096,512] bf16, 4 MB
    short* kh   = (short*)(ws + 4 * MB);      // 4 MB
    short* vT   = (short*)(ws + 8 * MB);      // [512,4096], 4 MB
    short* Wqb  = (short*)(ws + 12 * MB);     // [512,1536], dead after proj
    short* Wkb  = (short*)(ws + 13 * MB + 512 * 1024);
    short* attn = (short*)(ws + 12 * MB);     // flash writes over dead Wqb/Wkb
    // d_out (24 MB) as scratch until outproj:
    short* qb   = (short*)d_out;                      // 12 MB, dead after proj
    short* kb   = (short*)((char*)d_out + 12 * MB);   // 12 MB, dead after proj

    // 1) fp32 -> bf16 copies
    convertA_kernel<<<dim3(3072, 1, 4), 256, 0, stream>>>(q, k, Wq, Wk, qb, kb, Wqb, Wkb);
    // 2) projections (rope fused into q/k epilogues), BM=64 tiles, 768 blocks
    proj_kernel<<<dim3(4, 64, 3), 256, 0, stream>>>(qb, kb, v, Wqb, Wkb, Wv, qh, kh, vT);
    // 3) flash attention v11 (chunk-paired, constant 9 supersteps/block)
    flash_kernel<<<dim3(256, 1, 1), 1024, 0, stream>>>(qh, kh, vT, attn);
    // 4) output projection (convertB fused: B staged fp32->bf16)
    outproj_kernel<<<dim3(12, 32, 1), 256, 0, stream>>>(attn, Wo, out);
}

// Round 6
// 222.768 us; speedup vs baseline: 1.0596x; 1.0596x over previous
//
#include <hip/hip_runtime.h>
#include <hip/hip_bf16.h>

typedef __attribute__((ext_vector_type(8))) short short8;
typedef __attribute__((ext_vector_type(4))) short short4v;
typedef __attribute__((ext_vector_type(4))) float f32x4;

__device__ __forceinline__ short f2bf(float f) {
    union { float f; unsigned u; } v; v.f = f;
    unsigned r = (v.u + 0x7fffu + ((v.u >> 16) & 1u)) >> 16;
    return (short)r;
}
__device__ __forceinline__ float bf2f(short s) {
    union { unsigned u; float f; } v; v.u = ((unsigned)(unsigned short)s) << 16;
    return v.f;
}
__device__ __forceinline__ f32x4 zero4() { f32x4 z = {0.f, 0.f, 0.f, 0.f}; return z; }

__device__ __forceinline__ void gl16(const void* g, void* l) {
    __builtin_amdgcn_global_load_lds(
        (const __attribute__((address_space(1))) void*)g,
        (__attribute__((address_space(3))) void*)l, 16, 0, 0);
}

// ---------------------------------------------------------------------------
// convertA: fp32 -> bf16 (before proj). z=0: qb  z=1: kb  z=2: Wqb  z=3: Wkb
// ---------------------------------------------------------------------------
__global__ __launch_bounds__(256) void convertA_kernel(
    const float* __restrict__ q, const float* __restrict__ k,
    const float* __restrict__ Wq, const float* __restrict__ Wk,
    short* __restrict__ qb, short* __restrict__ kb,
    short* __restrict__ Wqb, short* __restrict__ Wkb)
{
    const int e0 = (blockIdx.x * 256 + threadIdx.x) * 8;
    const float* src; short* dst; int n;
    switch (blockIdx.z) {
    case 0:  n = 6291456; src = q + e0;  dst = qb;  break;
    case 1:  n = 6291456; src = k + e0;  dst = kb;  break;
    case 2:  n = 786432;  src = Wq + e0; dst = Wqb; break;
    default: n = 786432;  src = Wk + e0; dst = Wkb; break;
    }
    if (e0 >= n) return;
    float4 f0 = ((const float4*)src)[0];
    float4 f1 = ((const float4*)src)[1];
    short8 o;
    o[0]=f2bf(f0.x); o[1]=f2bf(f0.y); o[2]=f2bf(f0.z); o[3]=f2bf(f0.w);
    o[4]=f2bf(f1.x); o[5]=f2bf(f1.y); o[6]=f2bf(f1.z); o[7]=f2bf(f1.w);
    *(short8*)(dst + e0) = o;
}

// ---------------------------------------------------------------------------
// bf16 GEMM, BM=64 BN=128 BK=64, gl16 staging (round-3 proven core).
// RoPE fused in epilogue. MODE 1: row-major bf16 store (qh).
// MODE 2: MFMA-fragment-major store (khF) so flash K-operand loads are
// fully coalesced: addr = (b*4+h)*262144 + t*4096 + ct*2048 + kk*512
//                       + quad*128 + l15*8 + e   (shorts)
// mapping elem K[s2 = t*32+ct*16+l15][d = kk*32+quad*8+e].
// ---------------------------------------------------------------------------
template<int MODE>
__device__ __forceinline__ void gemm97_bm64(
    const short* __restrict__ A, const short* __restrict__ B, short* __restrict__ Cp,
    int K, int lda, int ldb, int ldc, short* As, short* Bs)
{
    const int bm = blockIdx.y * 64;
    const int bn = blockIdx.x * 128;
    const int tid = threadIdx.x;
    const int w = tid >> 6;
    const int lane = tid & 63;
    const int l15 = lane & 15;
    const int quad = lane >> 4;
    const int wm = (w >> 1) * 32;
    const int wn = (w & 1) * 64;

    const int srA = w * 16 + (lane >> 2);
    const int srB = w * 32 + (lane >> 2);
    const int sc  = (lane & 3) * 8;
    const short* ga = A + (size_t)(bm + srA) * lda + sc;
    const short* gb = B + (size_t)(bn + srB) * ldb + sc;

    f32x4 acc[2][4];
#pragma unroll
    for (int i = 0; i < 2; i++)
#pragma unroll
        for (int j = 0; j < 4; j++) acc[i][j] = zero4();

    for (int k0 = 0; k0 < K; k0 += 64) {
        __syncthreads();
#pragma unroll
        for (int p = 0; p < 2; p++) {
            gl16(ga + k0 + p * 32,                    &As[p * 2048 + (w * 16) * 32]);
            gl16(gb + k0 + p * 32,                    &Bs[p * 4096 + (w * 32) * 32]);
            gl16(gb + k0 + p * 32 + (size_t)16 * ldb, &Bs[p * 4096 + (w * 32 + 16) * 32]);
        }
        __syncthreads();

        short8 af[2][2], bf[2][4];
#pragma unroll
        for (int p = 0; p < 2; p++) {
#pragma unroll
            for (int i = 0; i < 2; i++)
                af[p][i] = *(const short8*)&As[p * 2048 + (wm + i * 16 + l15) * 32 + quad * 8];
#pragma unroll
            for (int j = 0; j < 4; j++)
                bf[p][j] = *(const short8*)&Bs[p * 4096 + (wn + j * 16 + l15) * 32 + quad * 8];
        }
#pragma unroll
        for (int i = 0; i < 2; i++)
#pragma unroll
            for (int j = 0; j < 4; j++) {
                acc[i][j] = __builtin_amdgcn_mfma_f32_16x16x32_bf16(af[0][i], bf[0][j], acc[i][j], 0, 0, 0);
                acc[i][j] = __builtin_amdgcn_mfma_f32_16x16x32_bf16(af[1][i], bf[1][j], acc[i][j], 0, 0, 0);
            }
    }

#pragma unroll
    for (int i = 0; i < 2; i++)
#pragma unroll
        for (int j = 0; j < 4; j++) {
            const int col = bn + wn + j * 16 + l15;
            const int row0 = bm + wm + i * 16 + quad * 4;
            const int pairi = (col & 127) >> 1;   // same for both lanes of a pair
            const float freq = exp2f(-(float)(2 * pairi) * (13.287712379549449f / 128.0f));
            const bool even = (l15 & 1) == 0;
#pragma unroll
            for (int r = 0; r < 4; r++) {
                const float own = acc[i][j][r];
                const float other = __shfl_xor(own, 1, 64);
                const float pos = (float)((row0 + r) & 2047);
                const float ang = pos * freq;
                const float n = rintf(ang * 0.15915494309189535f);
                const float rr = (ang - n * 6.28125f) - n * 1.9353071795864769e-3f;
                float s, c;
                __sincosf(rr, &s, &c);
                const float x1 = even ? own : other;
                const float x2 = even ? other : own;
                const float res = even ? (x1 * c - x2 * s) : (x1 * s + x2 * c);
                if constexpr (MODE == 1) {
                    Cp[(size_t)(row0 + r) * ldc + col] = f2bf(res);
                } else {
                    const int seq = row0 + r;
                    const int b_ = seq >> 11;
                    const int s2 = seq & 2047;
                    Cp[(size_t)(b_ * 4 + (col >> 7)) * 262144 + (s2 >> 5) * 4096
                       + ((s2 >> 4) & 1) * 2048 + ((col >> 5) & 3) * 512
                       + ((col >> 3) & 3) * 128 + (s2 & 15) * 8 + (col & 7)] = f2bf(res);
                }
            }
        }
}

// ---------------------------------------------------------------------------
// fp32-input GEMM, BM=64 BN=128 BK=32 (proven core), epilogue changed to
// MFMA-fragment-major V store (vF) for coalesced flash V-operand loads:
// addr = (b*4+h)*262144 + t*4096 + dt*512 + quad_v*128 + l15*8 + e  (shorts)
// mapping elem V[kv = t*32+quad_v*8+e][d = dt*16+l15]; within the r-loop
// (s2&7) spans a contiguous run of 4 -> single short4v store.
// ---------------------------------------------------------------------------
__device__ __forceinline__ void gemm_f32T_vF(
    const float* __restrict__ A, const float* __restrict__ Bw, short* __restrict__ Cp,
    int K, int lda, int ldb, short* As, short* Bs)
{
    const int bm = blockIdx.y * 64;
    const int bn = blockIdx.x * 128;
    const int tid = threadIdx.x;
    const int w = tid >> 6;
    const int lane = tid & 63;
    const int l15 = lane & 15;
    const int quad = lane >> 4;
    const int wm = (w >> 1) * 32;
    const int wn = (w & 1) * 64;
    const int srA = tid >> 2;
    const int scA = (tid & 3) * 8;
    const int srB = tid >> 1;
    const int scB = (tid & 1) * 16;

    f32x4 acc[2][4];
#pragma unroll
    for (int i = 0; i < 2; i++)
#pragma unroll
        for (int j = 0; j < 4; j++) acc[i][j] = zero4();

    for (int k0 = 0; k0 < K; k0 += 32) {
        __syncthreads();
        {
            const float* src = A + (size_t)(bm + srA) * lda + k0 + scA;
            short* dst = &As[srA * 40 + scA];
            const float4* s4 = (const float4*)src;
            float4 f0 = s4[0], f1 = s4[1];
            short8 t0;
            t0[0]=f2bf(f0.x); t0[1]=f2bf(f0.y); t0[2]=f2bf(f0.z); t0[3]=f2bf(f0.w);
            t0[4]=f2bf(f1.x); t0[5]=f2bf(f1.y); t0[6]=f2bf(f1.z); t0[7]=f2bf(f1.w);
            *(short8*)dst = t0;
        }
        {
            const float* src = Bw + (size_t)(bn + srB) * ldb + k0 + scB;
            short* dst = &Bs[srB * 40 + scB];
            const float4* s4 = (const float4*)src;
            float4 f0 = s4[0], f1 = s4[1], f2 = s4[2], f3 = s4[3];
            short8 t0, t1;
            t0[0]=f2bf(f0.x); t0[1]=f2bf(f0.y); t0[2]=f2bf(f0.z); t0[3]=f2bf(f0.w);
            t0[4]=f2bf(f1.x); t0[5]=f2bf(f1.y); t0[6]=f2bf(f1.z); t0[7]=f2bf(f1.w);
            t1[0]=f2bf(f2.x); t1[1]=f2bf(f2.y); t1[2]=f2bf(f2.z); t1[3]=f2bf(f2.w);
            t1[4]=f2bf(f3.x); t1[5]=f2bf(f3.y); t1[6]=f2bf(f3.z); t1[7]=f2bf(f3.w);
            *(short8*)dst = t0; *(short8*)(dst + 8) = t1;
        }
        __syncthreads();

        short8 af[2], bfr[4];
#pragma unroll
        for (int i = 0; i < 2; i++)
            af[i] = *(const short8*)&As[(wm + i * 16 + l15) * 40 + quad * 8];
#pragma unroll
        for (int j = 0; j < 4; j++)
            bfr[j] = *(const short8*)&Bs[(wn + j * 16 + l15) * 40 + quad * 8];
#pragma unroll
        for (int i = 0; i < 2; i++)
#pragma unroll
            for (int j = 0; j < 4; j++)
                acc[i][j] = __builtin_amdgcn_mfma_f32_16x16x32_bf16(af[i], bfr[j], acc[i][j], 0, 0, 0);
    }

#pragma unroll
    for (int i = 0; i < 2; i++)
#pragma unroll
        for (int j = 0; j < 4; j++) {
            const int col = bn + wn + j * 16 + l15;     // d feature 0..511
            const int row0 = bm + wm + i * 16 + quad * 4; // kv seq 0..4095
            const int b_ = row0 >> 11;
            const int s2 = row0 & 2047;
            short4v p;
#pragma unroll
            for (int r = 0; r < 4; r++) p[r] = f2bf(acc[i][j][r]);
            const size_t addr = (size_t)(b_ * 4 + (col >> 7)) * 262144 + (s2 >> 5) * 4096
                              + ((col >> 4) & 7) * 512 + ((s2 >> 3) & 3) * 128
                              + (col & 15) * 8 + (s2 & 7);
            *(short4v*)&Cp[addr] = p;
        }
}

// z=0: qh = rope(qb@Wqb^T) row-major; z=1: khF = rope(kb@Wkb^T) fragment-major;
// z=2: vF = (v_mid@Wv^T) fragment-major.  Grid (4, 64, 3) = 768 blocks ~ 3/CU.
__global__ __launch_bounds__(256) void proj_kernel(
    const short* __restrict__ qb, const short* __restrict__ kb, const float* __restrict__ v,
    const short* __restrict__ Wqb, const short* __restrict__ Wkb, const float* __restrict__ Wv,
    short* __restrict__ qh, short* __restrict__ khF, short* __restrict__ vF)
{
    __shared__ short smem[12288];   // 24 KB
    switch (blockIdx.z) {
    case 0:  gemm97_bm64<1>(qb, Wqb, qh,  1536, 1536, 1536, 512, smem, smem + 4096); break;
    case 1:  gemm97_bm64<2>(kb, Wkb, khF, 1536, 1536, 1536, 512, smem, smem + 4096); break;
    default: gemm_f32T_vF(v + 512, Wv, vF, 512, 1536, 512, smem, smem + 2560); break;
    }
}

// out[4096,1536] = attn[4096,512] @ Wo[:, :512]^T — convertB fused (B fp32 staging)
__global__ __launch_bounds__(256) void outproj_kernel(
    const short* __restrict__ attn, const float* __restrict__ Wo, float* __restrict__ out)
{
    __shared__ short smem[2][5120];
    const int bm = blockIdx.y * 128;
    const int bn = blockIdx.x * 128;
    const int tid = threadIdx.x;
    const int w = tid >> 6;
    const int lane = tid & 63;
    const int l15 = lane & 15;
    const int quad = lane >> 4;
    const int wm = (w >> 1) * 64;
    const int wn = (w & 1) * 64;
    const int srow = tid >> 1;
    const int scol = (tid & 1) * 16;
    short* As = smem[0];
    short* Bs = smem[1];
    const int K = 512, lda = 512, ldb = 1536, ldc = 1536;

    f32x4 acc[4][4];
#pragma unroll
    for (int i = 0; i < 4; i++)
#pragma unroll
        for (int j = 0; j < 4; j++) acc[i][j] = zero4();

    for (int k0 = 0; k0 < K; k0 += 32) {
        __syncthreads();
        {
            const short* src = attn + (size_t)(bm + srow) * lda + k0 + scol;
            short* dst = &As[srow * 40 + scol];
            const uint4* s4 = (const uint4*)src;
            uint4 a = s4[0], b = s4[1];
            *(uint4*)dst = a; *(uint4*)(dst + 8) = b;
        }
        {
            const float* src = Wo + (size_t)(bn + srow) * ldb + k0 + scol;
            short* dst = &Bs[srow * 40 + scol];
            const float4* s4 = (const float4*)src;
            float4 f0 = s4[0], f1 = s4[1], f2 = s4[2], f3 = s4[3];
            short8 t0, t1;
            t0[0]=f2bf(f0.x); t0[1]=f2bf(f0.y); t0[2]=f2bf(f0.z); t0[3]=f2bf(f0.w);
            t0[4]=f2bf(f1.x); t0[5]=f2bf(f1.y); t0[6]=f2bf(f1.z); t0[7]=f2bf(f1.w);
            t1[0]=f2bf(f2.x); t1[1]=f2bf(f2.y); t1[2]=f2bf(f2.z); t1[3]=f2bf(f2.w);
            t1[4]=f2bf(f3.x); t1[5]=f2bf(f3.y); t1[6]=f2bf(f3.z); t1[7]=f2bf(f3.w);
            *(short8*)dst = t0; *(short8*)(dst + 8) = t1;
        }
        __syncthreads();

        short8 af[4], bfr[4];
#pragma unroll
        for (int i = 0; i < 4; i++)
            af[i] = *(const short8*)&As[(wm + i * 16 + l15) * 40 + quad * 8];
#pragma unroll
        for (int j = 0; j < 4; j++)
            bfr[j] = *(const short8*)&Bs[(wn + j * 16 + l15) * 40 + quad * 8];
#pragma unroll
        for (int i = 0; i < 4; i++)
#pragma unroll
            for (int j = 0; j < 4; j++)
                acc[i][j] = __builtin_amdgcn_mfma_f32_16x16x32_bf16(af[i], bfr[j], acc[i][j], 0, 0, 0);
    }

#pragma unroll
    for (int i = 0; i < 4; i++)
#pragma unroll
        for (int j = 0; j < 4; j++) {
            const int col = bn + wn + j * 16 + l15;
            const int row0 = bm + wm + i * 16 + quad * 4;
#pragma unroll
            for (int r = 0; r < 4; r++)
                out[(size_t)(row0 + r) * ldc + col] = acc[i][j][r];
        }
}

// ---------------------------------------------------------------------------
// Flash attention v12: NO staging. khF/vF are fragment-major in global, so
// every K/V fragment is ONE coalesced global_load_dwordx4 (64 x 16B = 1 KB),
// L2-resident (1 MB KV per XCD, XCD-pinned via id&7) and L1-shared across the
// 4 co-resident blocks (same hb, lockstep parity walk). v8 grid: 1024 blocks
// x 4 waves; block = 16 q-rows (qt via balanced map {m,32+m,95-m,127-m});
// waves split KV tiles 4-way by parity; no barriers in the KV loop.
// Rationale (r5 post-mortem): superstep time followed ~100cy per gl16
// serialized per CU -> staging path was the wall; direct coalesced loads
// bypass it entirely. Fixed-max softmax (M=24) unchanged.
// ---------------------------------------------------------------------------
__global__ __launch_bounds__(256, 4) void flash_kernel(
    const short* __restrict__ qh, const short* __restrict__ khF,
    const short* __restrict__ vF, short* __restrict__ attn)
{
    __shared__ float Os[4][16][128];   // per-wave O partials (32 KB)
    __shared__ short Ps[4][16 * 40];   // per-wave P scratch (5 KB)
    __shared__ float Lp[4][16];        // per-wave row sums

    const int id = blockIdx.x;         // 0..1023
    const int hb = id & 7;
    const int b = hb & 1;
    const int h = hb >> 1;
    const int s = id >> 3;             // 0..127
    const int m = s & 31;
    const int g = s >> 5;              // 0..3
    const int base = (g >> 1) * 32 + m;            // {m, 32+m}
    const int qt = (g & 1) ? (127 - base) : base;  // bijective onto 0..127
    const int tid = threadIdx.x;
    const int w = tid >> 6;
    const int lane = tid & 63;
    const int l15 = lane & 15;
    const int quad = lane >> 4;

    const float scale = 0.08838834764831845f;
    const float MFIX = 24.0f;

    const int q0 = qt * 16;
    const int ntiles = (q0 + 47) >> 5;

    const short* qrow = qh + (size_t)(b * 2048 + q0 + l15) * 512 + h * 128;
    short8 aq[4];
#pragma unroll
    for (int kk = 0; kk < 4; kk++)
        aq[kk] = *(const short8*)&qrow[kk * 32 + quad * 8];

    const short* kfb = khF + (size_t)(b * 4 + h) * 262144 + lane * 8;
    const short* vfb = vF  + (size_t)(b * 4 + h) * 262144 + lane * 8;

    f32x4 o[8];
#pragma unroll
    for (int dt = 0; dt < 8; dt++) o[dt] = zero4();
    float lsum[4] = {0.f, 0.f, 0.f, 0.f};

    short* pw = &Ps[w][0];

    for (int t = w; t < ntiles; t += 4) {
        const int kb0 = t * 32;
        const short* kt_ = kfb + t * 4096;
        const short* vt_ = vfb + t * 4096;

        // ---- S = Q K^T (16q x 32k); K frags = coalesced global loads ----
        f32x4 sc[2];
#pragma unroll
        for (int ct = 0; ct < 2; ct++) {
            sc[ct] = zero4();
#pragma unroll
            for (int kk = 0; kk < 4; kk++) {
                short8 bk = *(const short8*)&kt_[ct * 2048 + kk * 512];
                sc[ct] = __builtin_amdgcn_mfma_f32_16x16x32_bf16(aq[kk], bk, sc[ct], 0, 0, 0);
            }
        }

        // ---- V frags = coalesced global loads ----
        short8 bv[8];
#pragma unroll
        for (int dt = 0; dt < 8; dt++)
            bv[dt] = *(const short8*)&vt_[dt * 512];

        // ---- fixed-max softmax: p = exp(s*scale - M), masked -> 0 ----
        const int rbase = q0 + quad * 4;
        float p[2][4];
#pragma unroll
        for (int ct = 0; ct < 2; ct++) {
            const int kcol = kb0 + ct * 16 + l15;
#pragma unroll
            for (int r = 0; r < 4; r++) {
                const float e = __expf(sc[ct][r] * scale - MFIX);
                const float pv = (kcol > rbase + r) ? 0.0f : e;
                p[ct][r] = pv;
                lsum[r] += pv;
            }
        }

        // ---- P -> per-wave LDS (A-operand layout); intra-wave ----
#pragma unroll
        for (int ct = 0; ct < 2; ct++)
#pragma unroll
            for (int r = 0; r < 4; r++)
                pw[(quad * 4 + r) * 40 + ct * 16 + l15] = f2bf(p[ct][r]);
        short8 ap = *(const short8*)&pw[l15 * 40 + quad * 8];

        // ---- O += P V ----
#pragma unroll
        for (int dt = 0; dt < 8; dt++)
            o[dt] = __builtin_amdgcn_mfma_f32_16x16x32_bf16(ap, bv[dt], o[dt], 0, 0, 0);
    }

    // ---- merge 4 waves: plain sums (common fixed max) ----
#pragma unroll
    for (int r = 0; r < 4; r++) {
        float vsum = lsum[r];
#pragma unroll
        for (int off = 1; off < 16; off <<= 1)
            vsum += __shfl_xor(vsum, off, 64);
        if (l15 == 0) Lp[w][quad * 4 + r] = vsum;
#pragma unroll
        for (int dt = 0; dt < 8; dt++)
            Os[w][quad * 4 + r][dt * 16 + l15] = o[dt][r];
    }
    __syncthreads();

    {
        const int row = tid >> 4;
        const int d0 = (tid & 15) * 8;
        const float L = Lp[0][row] + Lp[1][row] + Lp[2][row] + Lp[3][row];
        const float rL = 1.0f / L;
        short8 ov;
#pragma unroll
        for (int j = 0; j < 8; j++) {
            const float osum = Os[0][row][d0 + j] + Os[1][row][d0 + j]
                             + Os[2][row][d0 + j] + Os[3][row][d0 + j];
            ov[j] = f2bf(osum * rL);
        }
        *(short8*)&attn[(size_t)(b * 2048 + q0 + row) * 512 + h * 128 + d0] = ov;
    }
}

extern "C" void kernel_launch(void* const* d_in, const int* in_sizes, int n_in,
                              void* d_out, int out_size, void* d_ws, size_t ws_size,
                              hipStream_t stream) {
    const float* q  = (const float*)d_in[0];
    const float* k  = (const float*)d_in[1];
    const float* v  = (const float*)d_in[2];
    const float* Wq = (const float*)d_in[3];
    const float* Wk = (const float*)d_in[4];
    const float* Wv = (const float*)d_in[5];
    const float* Wo = (const float*)d_in[6];
    float* out = (float*)d_out;

    const size_t MB = 1024 * 1024;
    // ws (16 MB):
    char* ws = (char*)d_ws;
    short* qh   = (short*)(ws);               // [4096,512] bf16 row-major, 4 MB
    short* khF  = (short*)(ws + 4 * MB);      // fragment-major K, 4 MB
    short* vF   = (short*)(ws + 8 * MB);      // fragment-major V, 4 MB
    short* Wqb  = (short*)(ws + 12 * MB);     // [512,1536], dead after proj
    short* Wkb  = (short*)(ws + 13 * MB + 512 * 1024);
    short* attn = (short*)(ws + 12 * MB);     // flash writes over dead Wqb/Wkb
    // d_out (24 MB) as scratch until outproj:
    short* qb   = (short*)d_out;                      // 12 MB, dead after proj
    short* kb   = (short*)((char*)d_out + 12 * MB);   // 12 MB, dead after proj

    // 1) fp32 -> bf16 copies
    convertA_kernel<<<dim3(3072, 1, 4), 256, 0, stream>>>(q, k, Wq, Wk, qb, kb, Wqb, Wkb);
    // 2) projections (rope fused; khF/vF stored fragment-major)
    proj_kernel<<<dim3(4, 64, 3), 256, 0, stream>>>(qb, kb, v, Wqb, Wkb, Wv, qh, khF, vF);
    // 3) flash attention v12 (staging-free, coalesced fragment loads)
    flash_kernel<<<dim3(1024, 1, 1), 256, 0, stream>>>(qh, khF, vF, attn);
    // 4) output projection (convertB fused: B staged fp32->bf16)
    outproj_kernel<<<dim3(12, 32, 1), 256, 0, stream>>>(attn, Wo, out);
}